// Round 12
// baseline (297.086 us; speedup 1.0000x reference)
//
#include <hip/hip_runtime.h>
#include <hip/hip_bf16.h>
#include <stdint.h>

#define N_NODES 102400
#define N_EDGES 409600
#define N_GRAPHS 2048
#define MAXN 64

typedef __attribute__((ext_vector_type(8))) short short8;
typedef __attribute__((ext_vector_type(4))) float f32x4;

static __device__ __forceinline__ float bfu2f(unsigned short u) {
    union { unsigned int i; float f; } v;
    v.i = ((unsigned int)u) << 16;
    return v.f;
}
static __device__ __forceinline__ unsigned short f2bfu(float f) {
    __hip_bfloat16 h = __float2bfloat16(f);
    return *reinterpret_cast<unsigned short*>(&h);
}

static __device__ __forceinline__ void gload16(const void* g, void* l) {
    __builtin_amdgcn_global_load_lds((const __attribute__((address_space(1))) void*)g,
                                     (__attribute__((address_space(3))) void*)l, 16, 0, 0);
}

// ---------------- degree / CSR build ----------------

__global__ void deg_kernel(const int* __restrict__ dst, int* __restrict__ deg) {
    int e = blockIdx.x * blockDim.x + threadIdx.x;
    if (e < N_EDGES) atomicAdd(&deg[dst[e]], 1);
}

__global__ void scan1_kernel(const int* __restrict__ deg, int* __restrict__ excl,
                             int* __restrict__ bsum) {
    __shared__ int sh[1024];
    int tid = threadIdx.x;
    int gid = blockIdx.x * 1024 + tid;   // N = 100*1024 exactly
    int v = deg[gid];
    sh[tid] = v;
    __syncthreads();
    for (int off = 1; off < 1024; off <<= 1) {
        int t = (tid >= off) ? sh[tid - off] : 0;
        __syncthreads();
        sh[tid] += t;
        __syncthreads();
    }
    excl[gid] = sh[tid] - v;
    if (tid == 1023) bsum[blockIdx.x] = sh[tid];
}

__global__ void scan2_kernel(int* __restrict__ bsum) {  // 100 entries
    __shared__ int sh[128];
    int tid = threadIdx.x;
    int v = (tid < 100) ? bsum[tid] : 0;
    sh[tid] = v;
    __syncthreads();
    for (int off = 1; off < 128; off <<= 1) {
        int t = (tid >= off) ? sh[tid - off] : 0;
        __syncthreads();
        sh[tid] += t;
        __syncthreads();
    }
    if (tid < 100) bsum[tid] = sh[tid] - v;
}

// scan finalize + dinv fused
__global__ void scan3_kernel(const int* __restrict__ excl, const int* __restrict__ bsum,
                             const int* __restrict__ deg,
                             int* __restrict__ offs, int* __restrict__ cursor,
                             float* __restrict__ dinv) {
    int gid = blockIdx.x * blockDim.x + threadIdx.x;
    if (gid < N_NODES) {
        int o = excl[gid] + bsum[gid >> 10];
        offs[gid] = o;
        cursor[gid] = o;
        dinv[gid] = rsqrtf((float)deg[gid] + 1.0f);
    }
    if (gid == 0) offs[N_NODES] = N_EDGES;
}

// packed CSR entry: {src, w_bits}
__global__ void fill_kernel(const int* __restrict__ src, const int* __restrict__ dst,
                            int* __restrict__ cursor, int2* __restrict__ csr_pk,
                            const float* __restrict__ dinv) {
    int e = blockIdx.x * blockDim.x + threadIdx.x;
    if (e >= N_EDGES) return;
    int s = src[e], d = dst[e];
    int pos = atomicAdd(&cursor[d], 1);
    float w = dinv[s] * dinv[d];
    int2 pk;
    pk.x = s;
    pk.y = __float_as_int(w);
    csr_pk[pos] = pk;
}

// ---------------- to_dense_batch row mapping ----------------

__global__ void start_kernel(const int* __restrict__ batch, int* __restrict__ startb) {
    int i = blockIdx.x * blockDim.x + threadIdx.x;
    if (i >= N_NODES) return;
    if (i == 0 || batch[i] != batch[i - 1]) startb[batch[i]] = i;
    if (i == 0) startb[N_GRAPHS] = N_NODES;
}

__global__ void rowmap_kernel(const int* __restrict__ batch, const int* __restrict__ startb,
                              const int* __restrict__ pmax, int* __restrict__ rowmap) {
    int i = blockIdx.x * blockDim.x + threadIdx.x;
    if (i >= N_NODES) return;
    int b = batch[i];
    int mx = *pmax;
    int pos = i - startb[b];
    rowmap[i] = (pos < mx) ? (b * mx + pos) : -1;
}

// zero padding rows: one block per graph
__global__ void padzero_kernel(const int* __restrict__ startb, float* __restrict__ out) {
    int b = blockIdx.x;
    int count = startb[b + 1] - startb[b];
    if (count >= MAXN) return;
    int nel = (MAXN - count) * 100;  // float2 units
    float* base = out + ((size_t)b * MAXN + count) * 200;
    for (int i = threadIdx.x; i < nel; i += 256) {
        float2 z = {0.0f, 0.0f};
        *(float2*)(base + i * 2) = z;
    }
}

// ---------------- x -> bf16 pre-cast: [N,78] fp32 -> [N,96] bf16 (zero-padded) --------

__global__ __launch_bounds__(256) void cast_x_kernel(const float* __restrict__ X,
                                                     __hip_bfloat16* __restrict__ xb) {
    int idx = blockIdx.x * blockDim.x + threadIdx.x;  // N*48 threads, 2 cols each
    if (idx >= N_NODES * 48) return;
    int node = idx / 48;
    int c = idx - node * 48;
    int col = c * 2;
    float2 v = {0.0f, 0.0f};
    if (col < 78) v = *(const float2*)(X + (size_t)node * 78 + col);
    __hip_bfloat162 r;
    r.x = __float2bfloat16(v.x);
    r.y = __float2bfloat16(v.y);
    *(__hip_bfloat162*)(xb + (size_t)node * 96 + col) = r;
}

// ---------------- weight prep (all four in one launch) ----------------

static __device__ __forceinline__ void prep_one(int i, const float* __restrict__ W,
                                                const float* __restrict__ b,
                                                int K, int Nc, int Kp, int Na,
                                                __hip_bfloat16* __restrict__ WT,
                                                float* __restrict__ bp) {
    int total = Na * Kp;
    if (i < total) {
        int c = i / Kp, k = i - c * Kp;
        float v = (c < Nc && k < K) ? W[k * Nc + c] : 0.0f;
        WT[i] = __float2bfloat16(v);
    }
    if (i < Na) bp[i] = (i < Nc) ? b[i] : 0.0f;
}

__global__ void prep_all_kernel(
    const float* __restrict__ W1, const float* __restrict__ b1,
    const float* __restrict__ W2, const float* __restrict__ b2,
    const float* __restrict__ W3, const float* __restrict__ b3,
    const float* __restrict__ Wf, const float* __restrict__ bf,
    __hip_bfloat16* __restrict__ WT1, float* __restrict__ b1p,
    __hip_bfloat16* __restrict__ WT2, float* __restrict__ b2p,
    __hip_bfloat16* __restrict__ WT3, float* __restrict__ b3p,
    __hip_bfloat16* __restrict__ WTF, float* __restrict__ bFp) {
    int i = blockIdx.x * blockDim.x + threadIdx.x;
    if (i < 12288) prep_one(i, W1, b1, 78, 78, 96, 128, WT1, b1p);
    else if (i < 36864) prep_one(i - 12288, W2, b2, 78, 156, 96, 256, WT2, b2p);
    else if (i < 98304) prep_one(i - 36864, W3, b3, 156, 312, 160, 384, WT3, b3p);
    else if (i < 180224) prep_one(i - 98304, Wf, bf, 312, 200, 320, 256, WTF, bFp);
}

// ---------------- aggregation: thread-per-(node, 16B chunk), packed CSR ----

template <int LD>
__global__ __launch_bounds__(256) void agg_bf16_v4(
    const __hip_bfloat16* __restrict__ H,
    const int* __restrict__ offs, const int2* __restrict__ csr_pk,
    const float* __restrict__ dinv,
    __hip_bfloat16* __restrict__ out) {
    constexpr int C = LD / 8;
    int idx = blockIdx.x * blockDim.x + threadIdx.x;
    if (idx >= N_NODES * C) return;
    int node = idx / C;
    int c = idx - node * C;
    const unsigned short* Hu = (const unsigned short*)H;
    size_t rowoff = (size_t)node * LD + c * 8;
    float di = dinv[node];
    float sw = di * di;
    short8 h = *(const short8*)(Hu + rowoff);
    float a[8];
#pragma unroll
    for (int i = 0; i < 8; ++i) a[i] = sw * bfu2f((unsigned short)h[i]);
    int e0 = offs[node], e1 = offs[node + 1];
    int j = e0;
    for (; j + 4 <= e1; j += 4) {
        int2 p0 = csr_pk[j], p1 = csr_pk[j + 1], p2 = csr_pk[j + 2], p3 = csr_pk[j + 3];
        float w0 = __int_as_float(p0.y), w1 = __int_as_float(p1.y);
        float w2 = __int_as_float(p2.y), w3 = __int_as_float(p3.y);
        short8 v0 = *(const short8*)(Hu + (size_t)p0.x * LD + c * 8);
        short8 v1 = *(const short8*)(Hu + (size_t)p1.x * LD + c * 8);
        short8 v2 = *(const short8*)(Hu + (size_t)p2.x * LD + c * 8);
        short8 v3 = *(const short8*)(Hu + (size_t)p3.x * LD + c * 8);
#pragma unroll
        for (int i = 0; i < 8; ++i)
            a[i] += w0 * bfu2f((unsigned short)v0[i]) + w1 * bfu2f((unsigned short)v1[i]) +
                    w2 * bfu2f((unsigned short)v2[i]) + w3 * bfu2f((unsigned short)v3[i]);
    }
    for (; j < e1; ++j) {
        int2 pk = csr_pk[j];
        float w = __int_as_float(pk.y);
        short8 v = *(const short8*)(Hu + (size_t)pk.x * LD + c * 8);
#pragma unroll
        for (int i = 0; i < 8; ++i) a[i] += w * bfu2f((unsigned short)v[i]);
    }
    short8 r;
#pragma unroll
    for (int i = 0; i < 8; ++i) r[i] = (short)f2bfu(a[i]);
    *(short8*)((unsigned short*)out + rowoff) = r;
}

// ---------------- bf16 MFMA GEMM (R4 staging; swapped operands -> vector epilogue) ----

__global__ __launch_bounds__(256) void mfma_gemm_kernel(
    const __hip_bfloat16* __restrict__ A, int lda,
    const __hip_bfloat16* __restrict__ WT,
    const float* __restrict__ biasp, int nsteps,
    void* __restrict__ Cout, int ldc, int ccols,
    const int* __restrict__ rowmap, int relu) {
    __shared__ __align__(16) char lds[49152];  // 3 x 16KB

    const int tid = threadIdx.x;
    const int lane = tid & 63;
    const int wid = tid >> 6;
    const int wr = wid >> 1, wc = wid & 1;
    const int r0 = blockIdx.y * 128;
    const int c0 = blockIdx.x * 128;

    const bool isB = (wid >= 2);
    const int half = wid & 1;
    const int srow = half * 64 + (lane >> 2);
    const size_t ldabytes = (size_t)lda * 2;
    const char* gbase = isB ? (const char*)(WT + (size_t)(c0 + srow) * lda)
                            : (const char*)(A + (size_t)(r0 + srow) * lda);
    gbase += (lane & 3) << 4;
    char* lbase = lds + (isB ? 8192 : 0) + half * 4096;

#define STAGE(s, b)                                                            \
    do {                                                                       \
        const char* g_ = gbase + (size_t)(s) * 64;                             \
        char* l_ = lbase + (b) * 16384;                                        \
        gload16(g_, l_);                                                       \
        gload16(g_ + 16 * ldabytes, l_ + 1024);                                \
        gload16(g_ + 32 * ldabytes, l_ + 2048);                                \
        gload16(g_ + 48 * ldabytes, l_ + 3072);                                \
    } while (0)

    const int frow = lane & 15;
    const int fsl = (lane >> 4) << 4;
    int aoff[4], boff[4];
#pragma unroll
    for (int m = 0; m < 4; ++m) aoff[m] = (wr * 64 + m * 16 + frow) * 64 + fsl;
#pragma unroll
    for (int n = 0; n < 4; ++n) boff[n] = 8192 + (wc * 64 + n * 16 + frow) * 64 + fsl;

    f32x4 acc[4][4];
#pragma unroll
    for (int m = 0; m < 4; ++m)
#pragma unroll
        for (int n = 0; n < 4; ++n) {
            f32x4 z = {0.0f, 0.0f, 0.0f, 0.0f};
            acc[m][n] = z;
        }

#define COMPUTE(b)                                                                        \
    do {                                                                                  \
        const char* cb_ = lds + (b) * 16384;                                              \
        short8 af[4], bfr[4];                                                             \
        _Pragma("unroll") for (int m = 0; m < 4; ++m) af[m] = *(const short8*)(cb_ + aoff[m]); \
        _Pragma("unroll") for (int n = 0; n < 4; ++n) bfr[n] = *(const short8*)(cb_ + boff[n]); \
        _Pragma("unroll") for (int m = 0; m < 4; ++m)                                     \
            _Pragma("unroll") for (int n = 0; n < 4; ++n)                                 \
                acc[m][n] = __builtin_amdgcn_mfma_f32_16x16x32_bf16(bfr[n], af[m], acc[m][n], 0, 0, 0); \
    } while (0)

    STAGE(0, 0);
    STAGE(1, 1);
    int t = 0;
    for (; t < nsteps - 1; ++t) {
        asm volatile("s_waitcnt vmcnt(4)" ::: "memory");
        __builtin_amdgcn_s_barrier();
        __builtin_amdgcn_sched_barrier(0);
        if (t + 2 < nsteps) STAGE(t + 2, (t + 2) % 3);
        COMPUTE(t % 3);
        __builtin_amdgcn_sched_barrier(0);
    }
    asm volatile("s_waitcnt vmcnt(0)" ::: "memory");
    __builtin_amdgcn_s_barrier();
    __builtin_amdgcn_sched_barrier(0);
    COMPUTE(t % 3);
#undef STAGE
#undef COMPUTE

    const int nrow0 = r0 + wr * 64 + (lane & 15);
    const int ncol0 = c0 + wc * 64 + ((lane >> 4) << 2);
#pragma unroll
    for (int m = 0; m < 4; ++m) {
        int row = nrow0 + m * 16;
        int drow = rowmap ? rowmap[row] : row;
#pragma unroll
        for (int n = 0; n < 4; ++n) {
            int col0 = ncol0 + n * 16;
            if (col0 >= ccols) continue;
            float4 bv = *(const float4*)(biasp + col0);
            float v0 = acc[m][n][0] + bv.x;
            float v1 = acc[m][n][1] + bv.y;
            float v2 = acc[m][n][2] + bv.z;
            float v3 = acc[m][n][3] + bv.w;
            if (relu) {
                v0 = fmaxf(v0, 0.0f); v1 = fmaxf(v1, 0.0f);
                v2 = fmaxf(v2, 0.0f); v3 = fmaxf(v3, 0.0f);
            }
            if (rowmap) {
                if (drow >= 0) {
                    float4 o = {v0, v1, v2, v3};
                    *(float4*)((float*)Cout + (size_t)drow * ldc + col0) = o;
                }
            } else {
                ushort4 o;
                o.x = f2bfu(v0); o.y = f2bfu(v1); o.z = f2bfu(v2); o.w = f2bfu(v3);
                *(ushort4*)((__hip_bfloat16*)Cout + (size_t)row * ldc + col0) = o;
            }
        }
    }
}

// ---------------- fused layer3-GEMM + FC v5: 32-row blocks for occupancy ----------
// Block = 32 rows, 256 threads (4 waves), grid N/32 = 3200. LDS h3 = 32x640 = 20KB.
// Stage 1: wave w -> all 32 rows x cols [w*80,+80): acc[2][5]; frags from global.
// Stage 2: wave w -> all 32 rows x cols [w*64,+64) (guard <200): acc[2][4]; A from
//   swizzled LDS, WTF 2-deep register prefetch issued before the barrier.
// Swizzle: byte ^= (row&7)<<4 within each 640B row.

__global__ __launch_bounds__(256) void gemm3fc_kernel(
    const __hip_bfloat16* __restrict__ A,     // [N,160] bf16 (agg of h2)
    const __hip_bfloat16* __restrict__ W3T,   // [384,160] bf16
    const float* __restrict__ b3p,            // [384]
    const __hip_bfloat16* __restrict__ WTF,   // [256,320] bf16
    const float* __restrict__ bFp,            // [256]
    float* __restrict__ out,
    const int* __restrict__ rowmap) {
    __shared__ __align__(16) char h3[32 * 640];  // 20 KB
    const int tid = threadIdx.x;
    const int lane = tid & 63;
    const int w = tid >> 6;  // 0..3
    const int r0 = blockIdx.x * 32;
    const int frow = lane & 15;
    const int kq = lane >> 4;  // 0..3

    // ---- stage 1: 32 x 80 per wave ----
    {
        const __hip_bfloat16* ab[2];
        const __hip_bfloat16* bb[5];
#pragma unroll
        for (int m = 0; m < 2; ++m)
            ab[m] = A + (size_t)(r0 + m * 16 + frow) * 160 + kq * 8;
#pragma unroll
        for (int n = 0; n < 5; ++n)
            bb[n] = W3T + (size_t)(w * 80 + n * 16 + frow) * 160 + kq * 8;

        f32x4 acc[2][5];
#pragma unroll
        for (int m = 0; m < 2; ++m)
#pragma unroll
            for (int n = 0; n < 5; ++n) {
                f32x4 z = {0.0f, 0.0f, 0.0f, 0.0f};
                acc[m][n] = z;
            }
#pragma unroll
        for (int t = 0; t < 5; ++t) {
            short8 af[2], bfr[5];
#pragma unroll
            for (int m = 0; m < 2; ++m) af[m] = *(const short8*)(ab[m] + t * 32);
#pragma unroll
            for (int n = 0; n < 5; ++n) bfr[n] = *(const short8*)(bb[n] + t * 32);
#pragma unroll
            for (int m = 0; m < 2; ++m)
#pragma unroll
                for (int n = 0; n < 5; ++n)
                    acc[m][n] = __builtin_amdgcn_mfma_f32_16x16x32_bf16(bfr[n], af[m],
                                                                        acc[m][n], 0, 0, 0);
        }
        // relu+bias -> bf16x4 -> swizzled LDS (ds_write_b64)
#pragma unroll
        for (int m = 0; m < 2; ++m) {
            int row = m * 16 + frow;
            int swz = (row & 7) << 4;
#pragma unroll
            for (int n = 0; n < 5; ++n) {
                int col0 = w * 80 + n * 16 + (kq << 2);
                float4 bv = *(const float4*)(b3p + col0);
                ushort4 o;
                o.x = f2bfu(fmaxf(acc[m][n][0] + bv.x, 0.0f));
                o.y = f2bfu(fmaxf(acc[m][n][1] + bv.y, 0.0f));
                o.z = f2bfu(fmaxf(acc[m][n][2] + bv.z, 0.0f));
                o.w = f2bfu(fmaxf(acc[m][n][3] + bv.w, 0.0f));
                int byte = row * 640 + col0 * 2;
                *(ushort4*)(h3 + (byte ^ swz)) = o;
            }
        }
    }

    // stage-2 WTF pointers + 2-deep prefetch, issued BEFORE the barrier
    const __hip_bfloat16* bb2[4];
#pragma unroll
    for (int n = 0; n < 4; ++n)
        bb2[n] = WTF + (size_t)(w * 64 + n * 16 + frow) * 320 + kq * 8;
    short8 bfr2[2][4];
#pragma unroll
    for (int n = 0; n < 4; ++n) bfr2[0][n] = *(const short8*)(bb2[n]);
#pragma unroll
    for (int n = 0; n < 4; ++n) bfr2[1][n] = *(const short8*)(bb2[n] + 32);

    __syncthreads();

    // ---- stage 2: 32 x 64 per wave (cols w*64, guard <200), K=320 ----
    {
        int drow_[2];
#pragma unroll
        for (int m = 0; m < 2; ++m) drow_[m] = rowmap[r0 + m * 16 + frow];
        float4 bvF[4];
#pragma unroll
        for (int n = 0; n < 4; ++n)
            bvF[n] = *(const float4*)(bFp + (w * 64 + n * 16 + (kq << 2)));

        int abase[2], aswz[2];
#pragma unroll
        for (int m = 0; m < 2; ++m) {
            int row = m * 16 + frow;
            abase[m] = row * 640 + kq * 16;
            aswz[m] = (row & 7) << 4;
        }
        f32x4 acc[2][4];
#pragma unroll
        for (int m = 0; m < 2; ++m)
#pragma unroll
            for (int n = 0; n < 4; ++n) {
                f32x4 z = {0.0f, 0.0f, 0.0f, 0.0f};
                acc[m][n] = z;
            }
#pragma unroll
        for (int t = 0; t < 10; ++t) {
            short8 af[2];
#pragma unroll
            for (int m = 0; m < 2; ++m)
                af[m] = *(const short8*)(h3 + ((abase[m] + t * 64) ^ aswz[m]));
#pragma unroll
            for (int m = 0; m < 2; ++m)
#pragma unroll
                for (int n = 0; n < 4; ++n)
                    acc[m][n] = __builtin_amdgcn_mfma_f32_16x16x32_bf16(bfr2[t & 1][n], af[m],
                                                                        acc[m][n], 0, 0, 0);
            if (t + 2 < 10) {
#pragma unroll
                for (int n = 0; n < 4; ++n)
                    bfr2[t & 1][n] = *(const short8*)(bb2[n] + (t + 2) * 32);
            }
        }
        // epilogue: float4 stores
#pragma unroll
        for (int m = 0; m < 2; ++m) {
            int drow = drow_[m];
            if (drow < 0) continue;
#pragma unroll
            for (int n = 0; n < 4; ++n) {
                int col0 = w * 64 + n * 16 + (kq << 2);
                if (col0 >= 200) continue;
                float4 o;
                o.x = acc[m][n][0] + bvF[n].x;
                o.y = acc[m][n][1] + bvF[n].y;
                o.z = acc[m][n][2] + bvF[n].z;
                o.w = acc[m][n][3] + bvF[n].w;
                *(float4*)(out + (size_t)drow * 200 + col0) = o;
            }
        }
    }
}

// ---------------- launch ----------------

static inline char* align256(char* p) {
    return (char*)(((uintptr_t)p + 255) & ~(uintptr_t)255);
}

extern "C" void kernel_launch(void* const* d_in, const int* in_sizes, int n_in,
                              void* d_out, int out_size, void* d_ws, size_t ws_size,
                              hipStream_t stream) {
    const int N = N_NODES, E = N_EDGES;
    const float* x = (const float*)d_in[0];
    const int* ei = (const int*)d_in[1];
    const int* src = ei;
    const int* dst = ei + E;
    const int* batch = (const int*)d_in[2];
    const int* pmax = (const int*)d_in[3];
    const float* W1 = (const float*)d_in[4];
    const float* b1 = (const float*)d_in[5];
    const float* W2 = (const float*)d_in[6];
    const float* b2 = (const float*)d_in[7];
    const float* W3 = (const float*)d_in[8];
    const float* b3 = (const float*)d_in[9];
    const float* Wfc = (const float*)d_in[10];
    const float* bfc = (const float*)d_in[11];
    float* out = (float*)d_out;

    char* p = (char*)d_ws;
    float* dinv = (float*)p;          p = align256(p + (size_t)N * 4);
    int* deg = (int*)p;               p = align256(p + (size_t)N * 4);
    int* offs = (int*)p;              p = align256(p + (size_t)(N + 1) * 4);
    int* cursor = (int*)p;            p = align256(p + (size_t)N * 4);
    int* excl = (int*)p;              p = align256(p + (size_t)N * 4);
    int* bsum = (int*)p;              p = align256(p + 128 * 4);
    int2* csr_pk = (int2*)p;          p = align256(p + (size_t)E * 8);
    int* startb = (int*)p;            p = align256(p + (size_t)(N_GRAPHS + 1) * 4);
    int* rowmap = (int*)p;            p = align256(p + (size_t)N * 4);
    __hip_bfloat16* WT1 = (__hip_bfloat16*)p;  p = align256(p + 128 * 96 * 2);
    float* b1p = (float*)p;           p = align256(p + 128 * 4);
    __hip_bfloat16* WT2 = (__hip_bfloat16*)p;  p = align256(p + 256 * 96 * 2);
    float* b2p = (float*)p;           p = align256(p + 256 * 4);
    __hip_bfloat16* WT3 = (__hip_bfloat16*)p;  p = align256(p + 384 * 160 * 2);
    float* b3p = (float*)p;           p = align256(p + 384 * 4);
    __hip_bfloat16* WTF = (__hip_bfloat16*)p;  p = align256(p + 256 * 320 * 2);
    float* bFp = (float*)p;           p = align256(p + 256 * 4);
    __hip_bfloat16* bufAgg = (__hip_bfloat16*)p;  p = align256(p + (size_t)N * 320 * 2);
    __hip_bfloat16* bufH = (__hip_bfloat16*)p;    p = align256(p + (size_t)N * 320 * 2);

    // degree + CSR (dinv fused into scan3; packed entries)
    hipMemsetAsync(deg, 0, (size_t)N * 4, stream);
    deg_kernel<<<(E + 255) / 256, 256, 0, stream>>>(dst, deg);
    scan1_kernel<<<100, 1024, 0, stream>>>(deg, excl, bsum);
    scan2_kernel<<<1, 128, 0, stream>>>(bsum);
    scan3_kernel<<<(N + 255) / 256, 256, 0, stream>>>(excl, bsum, deg, offs, cursor, dinv);
    fill_kernel<<<(E + 255) / 256, 256, 0, stream>>>(src, dst, cursor, csr_pk, dinv);

    // dense-batch mapping
    start_kernel<<<(N + 255) / 256, 256, 0, stream>>>(batch, startb);
    rowmap_kernel<<<(N + 255) / 256, 256, 0, stream>>>(batch, startb, pmax, rowmap);

    // weight prep (single launch) + x pre-cast to bf16 [N,96] in bufH
    prep_all_kernel<<<(180224 + 255) / 256, 256, 0, stream>>>(
        W1, b1, W2, b2, W3, b3, Wfc, bfc, WT1, b1p, WT2, b2p, WT3, b3p, WTF, bFp);
    cast_x_kernel<<<(N * 48 + 255) / 256, 256, 0, stream>>>(x, bufH);

    // Layer 1: agg(xb) -> [N,96]; gemm -> h1 [N,96]
    agg_bf16_v4<96><<<(N * 12 + 255) / 256, 256, 0, stream>>>(bufH, offs, csr_pk, dinv, bufAgg);
    mfma_gemm_kernel<<<dim3(1, N / 128), 256, 0, stream>>>(
        bufAgg, 96, WT1, b1p, 3, bufH, 96, 96, nullptr, 1);

    // Layer 2: agg -> [N,96]; gemm -> h2 [N,160]
    agg_bf16_v4<96><<<(N * 12 + 255) / 256, 256, 0, stream>>>(bufH, offs, csr_pk, dinv, bufAgg);
    mfma_gemm_kernel<<<dim3(2, N / 128), 256, 0, stream>>>(
        bufAgg, 96, WT2, b2p, 3, bufH, 160, 160, nullptr, 1);

    // Layer 3 agg -> [N,160]; fused gemm3+FC (h3 never touches HBM)
    agg_bf16_v4<160><<<(N * 20 + 255) / 256, 256, 0, stream>>>(bufH, offs, csr_pk, dinv, bufAgg);
    padzero_kernel<<<N_GRAPHS, 256, 0, stream>>>(startb, out);
    gemm3fc_kernel<<<N / 32, 256, 0, stream>>>(bufAgg, WT3, b3p, WTF, bFp, out, rowmap);
}

// Round 13
// 257.928 us; speedup vs baseline: 1.1518x; 1.1518x over previous
//
#include <hip/hip_runtime.h>
#include <hip/hip_bf16.h>
#include <stdint.h>

#define N_NODES 102400
#define N_EDGES 409600
#define N_GRAPHS 2048
#define MAXN 64

typedef __attribute__((ext_vector_type(8))) short short8;
typedef __attribute__((ext_vector_type(4))) float f32x4;

static __device__ __forceinline__ float bfu2f(unsigned short u) {
    union { unsigned int i; float f; } v;
    v.i = ((unsigned int)u) << 16;
    return v.f;
}
static __device__ __forceinline__ unsigned short f2bfu(float f) {
    __hip_bfloat16 h = __float2bfloat16(f);
    return *reinterpret_cast<unsigned short*>(&h);
}

// ---------------- degree / CSR build ----------------

__global__ void deg_kernel(const int* __restrict__ dst, int* __restrict__ deg) {
    int e = blockIdx.x * blockDim.x + threadIdx.x;
    if (e < N_EDGES) atomicAdd(&deg[dst[e]], 1);
}

__global__ void scan1_kernel(const int* __restrict__ deg, int* __restrict__ excl,
                             int* __restrict__ bsum) {
    __shared__ int sh[1024];
    int tid = threadIdx.x;
    int gid = blockIdx.x * 1024 + tid;   // N = 100*1024 exactly
    int v = deg[gid];
    sh[tid] = v;
    __syncthreads();
    for (int off = 1; off < 1024; off <<= 1) {
        int t = (tid >= off) ? sh[tid - off] : 0;
        __syncthreads();
        sh[tid] += t;
        __syncthreads();
    }
    excl[gid] = sh[tid] - v;
    if (tid == 1023) bsum[blockIdx.x] = sh[tid];
}

__global__ void scan2_kernel(int* __restrict__ bsum) {  // 100 entries
    __shared__ int sh[128];
    int tid = threadIdx.x;
    int v = (tid < 100) ? bsum[tid] : 0;
    sh[tid] = v;
    __syncthreads();
    for (int off = 1; off < 128; off <<= 1) {
        int t = (tid >= off) ? sh[tid - off] : 0;
        __syncthreads();
        sh[tid] += t;
        __syncthreads();
    }
    if (tid < 100) bsum[tid] = sh[tid] - v;
}

// scan finalize + dinv fused
__global__ void scan3_kernel(const int* __restrict__ excl, const int* __restrict__ bsum,
                             const int* __restrict__ deg,
                             int* __restrict__ offs, int* __restrict__ cursor,
                             float* __restrict__ dinv) {
    int gid = blockIdx.x * blockDim.x + threadIdx.x;
    if (gid < N_NODES) {
        int o = excl[gid] + bsum[gid >> 10];
        offs[gid] = o;
        cursor[gid] = o;
        dinv[gid] = rsqrtf((float)deg[gid] + 1.0f);
    }
    if (gid == 0) offs[N_NODES] = N_EDGES;
}

// packed CSR entry: {src, w_bits}
__global__ void fill_kernel(const int* __restrict__ src, const int* __restrict__ dst,
                            int* __restrict__ cursor, int2* __restrict__ csr_pk,
                            const float* __restrict__ dinv) {
    int e = blockIdx.x * blockDim.x + threadIdx.x;
    if (e >= N_EDGES) return;
    int s = src[e], d = dst[e];
    int pos = atomicAdd(&cursor[d], 1);
    float w = dinv[s] * dinv[d];
    int2 pk;
    pk.x = s;
    pk.y = __float_as_int(w);
    csr_pk[pos] = pk;
}

// ---------------- to_dense_batch row mapping ----------------

__global__ void start_kernel(const int* __restrict__ batch, int* __restrict__ startb) {
    int i = blockIdx.x * blockDim.x + threadIdx.x;
    if (i >= N_NODES) return;
    if (i == 0 || batch[i] != batch[i - 1]) startb[batch[i]] = i;
    if (i == 0) startb[N_GRAPHS] = N_NODES;
}

__global__ void rowmap_kernel(const int* __restrict__ batch, const int* __restrict__ startb,
                              const int* __restrict__ pmax, int* __restrict__ rowmap) {
    int i = blockIdx.x * blockDim.x + threadIdx.x;
    if (i >= N_NODES) return;
    int b = batch[i];
    int mx = *pmax;
    int pos = i - startb[b];
    rowmap[i] = (pos < mx) ? (b * mx + pos) : -1;
}

// zero padding rows: one block per graph
__global__ void padzero_kernel(const int* __restrict__ startb, float* __restrict__ out) {
    int b = blockIdx.x;
    int count = startb[b + 1] - startb[b];
    if (count >= MAXN) return;
    int nel = (MAXN - count) * 100;  // float2 units
    float* base = out + ((size_t)b * MAXN + count) * 200;
    for (int i = threadIdx.x; i < nel; i += 256) {
        float2 z = {0.0f, 0.0f};
        *(float2*)(base + i * 2) = z;
    }
}

// ---------------- x -> bf16 pre-cast: [N,78] fp32 -> [N,96] bf16 (zero-padded) --------

__global__ __launch_bounds__(256) void cast_x_kernel(const float* __restrict__ X,
                                                     __hip_bfloat16* __restrict__ xb) {
    int idx = blockIdx.x * blockDim.x + threadIdx.x;  // N*48 threads, 2 cols each
    if (idx >= N_NODES * 48) return;
    int node = idx / 48;
    int c = idx - node * 48;
    int col = c * 2;
    float2 v = {0.0f, 0.0f};
    if (col < 78) v = *(const float2*)(X + (size_t)node * 78 + col);
    __hip_bfloat162 r;
    r.x = __float2bfloat16(v.x);
    r.y = __float2bfloat16(v.y);
    *(__hip_bfloat162*)(xb + (size_t)node * 96 + col) = r;
}

// ---------------- weight prep (all four in one launch) ----------------

static __device__ __forceinline__ void prep_one(int i, const float* __restrict__ W,
                                                const float* __restrict__ b,
                                                int K, int Nc, int Kp, int Na,
                                                __hip_bfloat16* __restrict__ WT,
                                                float* __restrict__ bp) {
    int total = Na * Kp;
    if (i < total) {
        int c = i / Kp, k = i - c * Kp;
        float v = (c < Nc && k < K) ? W[k * Nc + c] : 0.0f;
        WT[i] = __float2bfloat16(v);
    }
    if (i < Na) bp[i] = (i < Nc) ? b[i] : 0.0f;
}

__global__ void prep_all_kernel(
    const float* __restrict__ W1, const float* __restrict__ b1,
    const float* __restrict__ W2, const float* __restrict__ b2,
    const float* __restrict__ W3, const float* __restrict__ b3,
    const float* __restrict__ Wf, const float* __restrict__ bf,
    __hip_bfloat16* __restrict__ WT1, float* __restrict__ b1p,
    __hip_bfloat16* __restrict__ WT2, float* __restrict__ b2p,
    __hip_bfloat16* __restrict__ WT3, float* __restrict__ b3p,
    __hip_bfloat16* __restrict__ WTF, float* __restrict__ bFp) {
    int i = blockIdx.x * blockDim.x + threadIdx.x;
    if (i < 12288) prep_one(i, W1, b1, 78, 78, 96, 128, WT1, b1p);
    else if (i < 36864) prep_one(i - 12288, W2, b2, 78, 156, 96, 256, WT2, b2p);
    else if (i < 98304) prep_one(i - 36864, W3, b3, 156, 312, 160, 384, WT3, b3p);
    else if (i < 180224) prep_one(i - 98304, Wf, bf, 312, 200, 320, 256, WTF, bFp);
}

// ---------------- standalone aggregation (layer 3): thread-per-(node, 16B chunk) ----

template <int LD>
__global__ __launch_bounds__(256) void agg_bf16_v4(
    const __hip_bfloat16* __restrict__ H,
    const int* __restrict__ offs, const int2* __restrict__ csr_pk,
    const float* __restrict__ dinv,
    __hip_bfloat16* __restrict__ out) {
    constexpr int C = LD / 8;
    int idx = blockIdx.x * blockDim.x + threadIdx.x;
    if (idx >= N_NODES * C) return;
    int node = idx / C;
    int c = idx - node * C;
    const unsigned short* Hu = (const unsigned short*)H;
    size_t rowoff = (size_t)node * LD + c * 8;
    float di = dinv[node];
    float sw = di * di;
    short8 h = *(const short8*)(Hu + rowoff);
    float a[8];
#pragma unroll
    for (int i = 0; i < 8; ++i) a[i] = sw * bfu2f((unsigned short)h[i]);
    int e0 = offs[node], e1 = offs[node + 1];
    int j = e0;
    for (; j + 4 <= e1; j += 4) {
        int2 p0 = csr_pk[j], p1 = csr_pk[j + 1], p2 = csr_pk[j + 2], p3 = csr_pk[j + 3];
        float w0 = __int_as_float(p0.y), w1 = __int_as_float(p1.y);
        float w2 = __int_as_float(p2.y), w3 = __int_as_float(p3.y);
        short8 v0 = *(const short8*)(Hu + (size_t)p0.x * LD + c * 8);
        short8 v1 = *(const short8*)(Hu + (size_t)p1.x * LD + c * 8);
        short8 v2 = *(const short8*)(Hu + (size_t)p2.x * LD + c * 8);
        short8 v3 = *(const short8*)(Hu + (size_t)p3.x * LD + c * 8);
#pragma unroll
        for (int i = 0; i < 8; ++i)
            a[i] += w0 * bfu2f((unsigned short)v0[i]) + w1 * bfu2f((unsigned short)v1[i]) +
                    w2 * bfu2f((unsigned short)v2[i]) + w3 * bfu2f((unsigned short)v3[i]);
    }
    for (; j < e1; ++j) {
        int2 pk = csr_pk[j];
        float w = __int_as_float(pk.y);
        short8 v = *(const short8*)(Hu + (size_t)pk.x * LD + c * 8);
#pragma unroll
        for (int i = 0; i < 8; ++i) a[i] += w * bfu2f((unsigned short)v[i]);
    }
    short8 r;
#pragma unroll
    for (int i = 0; i < 8; ++i) r[i] = (short)f2bfu(a[i]);
    *(short8*)((unsigned short*)out + rowoff) = r;
}

// ---------------- fused aggregation + GEMM (layers 1 & 2) ----------------
// Block = 128 rows, 256 threads (4 waves), grid N/128 = 800.
// Phase A: agg of 128 node rows [LDH=96 cols] -> LDS, rows at 208B stride (elements at
//   byte row*208 + e*2). Thread (tid) handles row tid>>1, chunk half tid&1 (6x16B).
// Phase B: Out[128][FOUT] = aggT @ WT^T + bias, relu -> bf16 ushort4 stores.
//   Wave (wr=wid>>1, wc=wid&1): rows wr*64, cols wc*(FOUT/2); acc[4][NB], K=96 (3 steps).
//   208B stride => ds_read_b128 A-frags are exactly 2-way bank-aliased (free, m136).

template <int FOUT>  // 96 (NB=3) or 160 (NB=5)
__global__ __launch_bounds__(256) void agg_gemm_kernel(
    const __hip_bfloat16* __restrict__ H,      // [N, 96] gather source
    const int* __restrict__ offs, const int2* __restrict__ csr_pk,
    const float* __restrict__ dinv,
    const __hip_bfloat16* __restrict__ WT,     // [FoutPad, 96] k-major
    const float* __restrict__ biasp,
    __hip_bfloat16* __restrict__ OutH) {       // [N, FOUT]
    constexpr int LDH = 96;
    constexpr int NB = FOUT / 32;
    constexpr int STRIDE = 208;
    __shared__ __align__(16) char aggT[128 * STRIDE];  // 26.6 KB
    const int tid = threadIdx.x;
    const int r0 = blockIdx.x * 128;

    // ---- phase A ----
    {
        const int row = tid >> 1;
        const int cb = (tid & 1) * 6;        // chunk base (6 chunks of 8 elems)
        const int node = r0 + row;
        const unsigned short* Hu = (const unsigned short*)H;
        const unsigned short* selfp = Hu + (size_t)node * LDH + cb * 8;
        float di = dinv[node];
        float sw = di * di;
        float a[6][8];
        {
            short8 s[6];
#pragma unroll
            for (int q = 0; q < 6; ++q) s[q] = *(const short8*)(selfp + q * 8);
#pragma unroll
            for (int q = 0; q < 6; ++q)
#pragma unroll
                for (int i = 0; i < 8; ++i) a[q][i] = sw * bfu2f((unsigned short)s[q][i]);
        }
        int e0 = offs[node], e1 = offs[node + 1];
        int j = e0;
        for (; j + 2 <= e1; j += 2) {
            int2 p0 = csr_pk[j], p1 = csr_pk[j + 1];
            float w0 = __int_as_float(p0.y), w1 = __int_as_float(p1.y);
            const unsigned short* q0 = Hu + (size_t)p0.x * LDH + cb * 8;
            const unsigned short* q1 = Hu + (size_t)p1.x * LDH + cb * 8;
            short8 v0[6], v1[6];
#pragma unroll
            for (int q = 0; q < 6; ++q) v0[q] = *(const short8*)(q0 + q * 8);
#pragma unroll
            for (int q = 0; q < 6; ++q) v1[q] = *(const short8*)(q1 + q * 8);
#pragma unroll
            for (int q = 0; q < 6; ++q)
#pragma unroll
                for (int i = 0; i < 8; ++i)
                    a[q][i] += w0 * bfu2f((unsigned short)v0[q][i]) +
                               w1 * bfu2f((unsigned short)v1[q][i]);
        }
        for (; j < e1; ++j) {
            int2 pk = csr_pk[j];
            float w = __int_as_float(pk.y);
            const unsigned short* qp = Hu + (size_t)pk.x * LDH + cb * 8;
            short8 v[6];
#pragma unroll
            for (int q = 0; q < 6; ++q) v[q] = *(const short8*)(qp + q * 8);
#pragma unroll
            for (int q = 0; q < 6; ++q)
#pragma unroll
                for (int i = 0; i < 8; ++i) a[q][i] += w * bfu2f((unsigned short)v[q][i]);
        }
        char* dstrow = aggT + row * STRIDE + cb * 16;
#pragma unroll
        for (int q = 0; q < 6; ++q) {
            short8 r;
#pragma unroll
            for (int i = 0; i < 8; ++i) r[i] = (short)f2bfu(a[q][i]);
            *(short8*)(dstrow + q * 16) = r;
        }
    }
    __syncthreads();

    // ---- phase B ----
    {
        const int lane = tid & 63;
        const int wid = tid >> 6;
        const int wr = wid >> 1, wc = wid & 1;
        const int frow = lane & 15;
        const int kq = lane >> 4;
        const __hip_bfloat16* bb[NB];
#pragma unroll
        for (int n = 0; n < NB; ++n)
            bb[n] = WT + (size_t)(wc * (FOUT / 2) + n * 16 + frow) * LDH + kq * 8;
        int abase[4];
#pragma unroll
        for (int m = 0; m < 4; ++m)
            abase[m] = (wr * 64 + m * 16 + frow) * STRIDE + kq * 16;

        f32x4 acc[4][NB];
#pragma unroll
        for (int m = 0; m < 4; ++m)
#pragma unroll
            for (int n = 0; n < NB; ++n) {
                f32x4 z = {0.0f, 0.0f, 0.0f, 0.0f};
                acc[m][n] = z;
            }
#pragma unroll
        for (int t = 0; t < 3; ++t) {  // K = 96
            short8 af[4], bfr[NB];
#pragma unroll
            for (int m = 0; m < 4; ++m) af[m] = *(const short8*)(aggT + abase[m] + t * 64);
#pragma unroll
            for (int n = 0; n < NB; ++n) bfr[n] = *(const short8*)(bb[n] + t * 32);
#pragma unroll
            for (int m = 0; m < 4; ++m)
#pragma unroll
                for (int n = 0; n < NB; ++n)
                    acc[m][n] = __builtin_amdgcn_mfma_f32_16x16x32_bf16(bfr[n], af[m],
                                                                        acc[m][n], 0, 0, 0);
        }
        // epilogue: row = r0+wr*64+m*16+frow; col0 = wc*(FOUT/2)+n*16+kq*4
#pragma unroll
        for (int m = 0; m < 4; ++m) {
            int row = r0 + wr * 64 + m * 16 + frow;
#pragma unroll
            for (int n = 0; n < NB; ++n) {
                int col0 = wc * (FOUT / 2) + n * 16 + (kq << 2);
                float4 bv = *(const float4*)(biasp + col0);
                ushort4 o;
                o.x = f2bfu(fmaxf(acc[m][n][0] + bv.x, 0.0f));
                o.y = f2bfu(fmaxf(acc[m][n][1] + bv.y, 0.0f));
                o.z = f2bfu(fmaxf(acc[m][n][2] + bv.z, 0.0f));
                o.w = f2bfu(fmaxf(acc[m][n][3] + bv.w, 0.0f));
                *(ushort4*)((unsigned short*)OutH + (size_t)row * FOUT + col0) = o;
            }
        }
    }
}

// ---------------- fused layer3-GEMM + FC (R11 exact: 64 rows, 4 waves, prefetch) ------

__global__ __launch_bounds__(256) void gemm3fc_kernel(
    const __hip_bfloat16* __restrict__ A,     // [N,160] bf16 (agg of h2)
    const __hip_bfloat16* __restrict__ W3T,   // [384,160] bf16
    const float* __restrict__ b3p,            // [384]
    const __hip_bfloat16* __restrict__ WTF,   // [256,320] bf16
    const float* __restrict__ bFp,            // [256]
    float* __restrict__ out,
    const int* __restrict__ rowmap) {
    __shared__ __align__(16) char h3[64 * 640];  // 40 KB
    const int tid = threadIdx.x;
    const int lane = tid & 63;
    const int w = tid >> 6;  // 0..3
    const int r0 = blockIdx.x * 64;
    const int frow = lane & 15;
    const int kq = lane >> 4;  // 0..3

    // ---- stage 1: 64 x 80 per wave ----
    {
        const __hip_bfloat16* ab[4];
        const __hip_bfloat16* bb[5];
#pragma unroll
        for (int m = 0; m < 4; ++m)
            ab[m] = A + (size_t)(r0 + m * 16 + frow) * 160 + kq * 8;
#pragma unroll
        for (int n = 0; n < 5; ++n)
            bb[n] = W3T + (size_t)(w * 80 + n * 16 + frow) * 160 + kq * 8;

        f32x4 acc[4][5];
#pragma unroll
        for (int m = 0; m < 4; ++m)
#pragma unroll
            for (int n = 0; n < 5; ++n) {
                f32x4 z = {0.0f, 0.0f, 0.0f, 0.0f};
                acc[m][n] = z;
            }
#pragma unroll
        for (int t = 0; t < 5; ++t) {
            short8 af[4], bfr[5];
#pragma unroll
            for (int m = 0; m < 4; ++m) af[m] = *(const short8*)(ab[m] + t * 32);
#pragma unroll
            for (int n = 0; n < 5; ++n) bfr[n] = *(const short8*)(bb[n] + t * 32);
#pragma unroll
            for (int m = 0; m < 4; ++m)
#pragma unroll
                for (int n = 0; n < 5; ++n)
                    acc[m][n] = __builtin_amdgcn_mfma_f32_16x16x32_bf16(bfr[n], af[m],
                                                                        acc[m][n], 0, 0, 0);
        }
        // relu+bias -> bf16x4 -> swizzled LDS (ds_write_b64)
#pragma unroll
        for (int m = 0; m < 4; ++m) {
            int row = m * 16 + frow;
            int swz = (row & 7) << 4;
#pragma unroll
            for (int n = 0; n < 5; ++n) {
                int col0 = w * 80 + n * 16 + (kq << 2);
                float4 bv = *(const float4*)(b3p + col0);
                ushort4 o;
                o.x = f2bfu(fmaxf(acc[m][n][0] + bv.x, 0.0f));
                o.y = f2bfu(fmaxf(acc[m][n][1] + bv.y, 0.0f));
                o.z = f2bfu(fmaxf(acc[m][n][2] + bv.z, 0.0f));
                o.w = f2bfu(fmaxf(acc[m][n][3] + bv.w, 0.0f));
                int byte = row * 640 + col0 * 2;
                *(ushort4*)(h3 + (byte ^ swz)) = o;
            }
        }
    }

    // stage-2 WTF pointers + 2-deep prefetch, issued BEFORE the barrier
    const __hip_bfloat16* bb2[4];
#pragma unroll
    for (int n = 0; n < 4; ++n)
        bb2[n] = WTF + (size_t)(w * 64 + n * 16 + frow) * 320 + kq * 8;
    short8 bfr2[2][4];
#pragma unroll
    for (int n = 0; n < 4; ++n) bfr2[0][n] = *(const short8*)(bb2[n]);
#pragma unroll
    for (int n = 0; n < 4; ++n) bfr2[1][n] = *(const short8*)(bb2[n] + 32);

    __syncthreads();

    // ---- stage 2: 64 x 64 per wave (cols w*64, guard <200), K=320 ----
    {
        int drow_[4];
#pragma unroll
        for (int m = 0; m < 4; ++m) drow_[m] = rowmap[r0 + m * 16 + frow];
        float4 bvF[4];
#pragma unroll
        for (int n = 0; n < 4; ++n)
            bvF[n] = *(const float4*)(bFp + (w * 64 + n * 16 + (kq << 2)));

        int abase[4], aswz[4];
#pragma unroll
        for (int m = 0; m < 4; ++m) {
            int row = m * 16 + frow;
            abase[m] = row * 640 + kq * 16;
            aswz[m] = (row & 7) << 4;
        }
        f32x4 acc[4][4];
#pragma unroll
        for (int m = 0; m < 4; ++m)
#pragma unroll
            for (int n = 0; n < 4; ++n) {
                f32x4 z = {0.0f, 0.0f, 0.0f, 0.0f};
                acc[m][n] = z;
            }
#pragma unroll
        for (int t = 0; t < 10; ++t) {
            short8 af[4];
#pragma unroll
            for (int m = 0; m < 4; ++m)
                af[m] = *(const short8*)(h3 + ((abase[m] + t * 64) ^ aswz[m]));
#pragma unroll
            for (int m = 0; m < 4; ++m)
#pragma unroll
                for (int n = 0; n < 4; ++n)
                    acc[m][n] = __builtin_amdgcn_mfma_f32_16x16x32_bf16(bfr2[t & 1][n], af[m],
                                                                        acc[m][n], 0, 0, 0);
            if (t + 2 < 10) {
#pragma unroll
                for (int n = 0; n < 4; ++n)
                    bfr2[t & 1][n] = *(const short8*)(bb2[n] + (t + 2) * 32);
            }
        }
        // epilogue: float4 stores
#pragma unroll
        for (int m = 0; m < 4; ++m) {
            int drow = drow_[m];
            if (drow < 0) continue;
#pragma unroll
            for (int n = 0; n < 4; ++n) {
                int col0 = w * 64 + n * 16 + (kq << 2);
                if (col0 >= 200) continue;
                float4 o;
                o.x = acc[m][n][0] + bvF[n].x;
                o.y = acc[m][n][1] + bvF[n].y;
                o.z = acc[m][n][2] + bvF[n].z;
                o.w = acc[m][n][3] + bvF[n].w;
                *(float4*)(out + (size_t)drow * 200 + col0) = o;
            }
        }
    }
}

// ---------------- launch ----------------

static inline char* align256(char* p) {
    return (char*)(((uintptr_t)p + 255) & ~(uintptr_t)255);
}

extern "C" void kernel_launch(void* const* d_in, const int* in_sizes, int n_in,
                              void* d_out, int out_size, void* d_ws, size_t ws_size,
                              hipStream_t stream) {
    const int N = N_NODES, E = N_EDGES;
    const float* x = (const float*)d_in[0];
    const int* ei = (const int*)d_in[1];
    const int* src = ei;
    const int* dst = ei + E;
    const int* batch = (const int*)d_in[2];
    const int* pmax = (const int*)d_in[3];
    const float* W1 = (const float*)d_in[4];
    const float* b1 = (const float*)d_in[5];
    const float* W2 = (const float*)d_in[6];
    const float* b2 = (const float*)d_in[7];
    const float* W3 = (const float*)d_in[8];
    const float* b3 = (const float*)d_in[9];
    const float* Wfc = (const float*)d_in[10];
    const float* bfc = (const float*)d_in[11];
    float* out = (float*)d_out;

    char* p = (char*)d_ws;
    float* dinv = (float*)p;          p = align256(p + (size_t)N * 4);
    int* deg = (int*)p;               p = align256(p + (size_t)N * 4);
    int* offs = (int*)p;              p = align256(p + (size_t)(N + 1) * 4);
    int* cursor = (int*)p;            p = align256(p + (size_t)N * 4);
    int* excl = (int*)p;              p = align256(p + (size_t)N * 4);
    int* bsum = (int*)p;              p = align256(p + 128 * 4);
    int2* csr_pk = (int2*)p;          p = align256(p + (size_t)E * 8);
    int* startb = (int*)p;            p = align256(p + (size_t)(N_GRAPHS + 1) * 4);
    int* rowmap = (int*)p;            p = align256(p + (size_t)N * 4);
    __hip_bfloat16* WT1 = (__hip_bfloat16*)p;  p = align256(p + 128 * 96 * 2);
    float* b1p = (float*)p;           p = align256(p + 128 * 4);
    __hip_bfloat16* WT2 = (__hip_bfloat16*)p;  p = align256(p + 256 * 96 * 2);
    float* b2p = (float*)p;           p = align256(p + 256 * 4);
    __hip_bfloat16* WT3 = (__hip_bfloat16*)p;  p = align256(p + 384 * 160 * 2);
    float* b3p = (float*)p;           p = align256(p + 384 * 4);
    __hip_bfloat16* WTF = (__hip_bfloat16*)p;  p = align256(p + 256 * 320 * 2);
    float* bFp = (float*)p;           p = align256(p + 256 * 4);
    __hip_bfloat16* bufAgg = (__hip_bfloat16*)p;  p = align256(p + (size_t)N * 320 * 2);
    __hip_bfloat16* bufH = (__hip_bfloat16*)p;    p = align256(p + (size_t)N * 320 * 2);

    // degree + CSR (dinv fused into scan3; packed entries)
    hipMemsetAsync(deg, 0, (size_t)N * 4, stream);
    deg_kernel<<<(E + 255) / 256, 256, 0, stream>>>(dst, deg);
    scan1_kernel<<<100, 1024, 0, stream>>>(deg, excl, bsum);
    scan2_kernel<<<1, 128, 0, stream>>>(bsum);
    scan3_kernel<<<(N + 255) / 256, 256, 0, stream>>>(excl, bsum, deg, offs, cursor, dinv);
    fill_kernel<<<(E + 255) / 256, 256, 0, stream>>>(src, dst, cursor, csr_pk, dinv);

    // dense-batch mapping
    start_kernel<<<(N + 255) / 256, 256, 0, stream>>>(batch, startb);
    rowmap_kernel<<<(N + 255) / 256, 256, 0, stream>>>(batch, startb, pmax, rowmap);

    // weight prep (single launch) + x pre-cast to bf16 [N,96] in bufH
    prep_all_kernel<<<(180224 + 255) / 256, 256, 0, stream>>>(
        W1, b1, W2, b2, W3, b3, Wfc, bfc, WT1, b1p, WT2, b2p, WT3, b3p, WTF, bFp);
    cast_x_kernel<<<(N * 48 + 255) / 256, 256, 0, stream>>>(x, bufH);

    // Layer 1 (fused agg+gemm): gathers xb from bufH -> h1 [N,96] in bufAgg
    agg_gemm_kernel<96><<<N / 128, 256, 0, stream>>>(
        bufH, offs, csr_pk, dinv, WT1, b1p, bufAgg);

    // Layer 2 (fused agg+gemm): gathers h1 from bufAgg -> h2 [N,160] in bufH
    agg_gemm_kernel<160><<<N / 128, 256, 0, stream>>>(
        bufAgg, offs, csr_pk, dinv, WT2, b2p, bufH);

    // Layer 3 agg -> [N,160]; fused gemm3+FC (h3 never touches HBM)
    agg_bf16_v4<160><<<(N * 20 + 255) / 256, 256, 0, stream>>>(bufH, offs, csr_pk, dinv, bufAgg);
    padzero_kernel<<<N_GRAPHS, 256, 0, stream>>>(startb, out);
    gemm3fc_kernel<<<N / 32 * 32 / 64, 256, 0, stream>>>(bufAgg, WT3, b3p, WTF, bFp, out, rowmap);
}